// Round 9
// baseline (461.109 us; speedup 1.0000x reference)
//
#include <hip/hip_runtime.h>
#include <hip/hip_bf16.h>

typedef __hip_bfloat16 bf16;
typedef __attribute__((ext_vector_type(8))) short bf16x8;
typedef __attribute__((ext_vector_type(4))) float f32x4;

#define H 128
#define F3H 384
#define E_RBF 20
#define NLAYER 3

__device__ __forceinline__ float silu_f(float x) { return x / (1.0f + __expf(-x)); }
__device__ __forceinline__ float b2f(bf16 x) { return __bfloat162float(x); }

constexpr float PI_F = 3.14159265358979323846f;
constexpr float CUT = 5.0f;

// ---------------- CSR hist ----------------
__global__ __launch_bounds__(256) void csr_hist(
    const int* __restrict__ edge, int* __restrict__ cnt, int nE) {
  int e = blockIdx.x * blockDim.x + threadIdx.x;
  if (e < nE) atomicAdd(&cnt[edge[2 * e]], 1);
}

// ---------------- CSR scan: 1024-thread LDS tree scan ----------------
__global__ __launch_bounds__(1024) void csr_scan(
    const int* __restrict__ cnt, int* __restrict__ rowstart, int* __restrict__ cur, int N) {
  __shared__ int part[1024];
  int t = threadIdx.x;
  int chunk = (N + 1023) / 1024;
  int lo = t * chunk; if (lo > N) lo = N;
  int hi = lo + chunk; if (hi > N) hi = N;
  int s = 0;
  for (int i = lo; i < hi; i++) s += cnt[i];
  part[t] = s;
  __syncthreads();
  for (int off = 1; off < 1024; off <<= 1) {
    int v = (t >= off) ? part[t - off] : 0;
    __syncthreads();
    part[t] += v;
    __syncthreads();
  }
  int r = (t == 0) ? 0 : part[t - 1];
  for (int i = lo; i < hi; i++) { rowstart[i] = r; cur[i] = r; r += cnt[i]; }
}

// ---------------- CSR fill + edge geometry pack (fused; no elist) ----------------
__global__ __launch_bounds__(256) void csr_fill_pack(
    const int* __restrict__ edge, int* __restrict__ cur,
    const float* __restrict__ edist, const float* __restrict__ ediff,
    int* __restrict__ srcs, float* __restrict__ geo, int nE) {
  int e = blockIdx.x * blockDim.x + threadIdx.x;
  if (e >= nE) return;
  int d = edge[2 * e];
  int p = atomicAdd(&cur[d], 1);
  srcs[p] = edge[2 * e + 1];
  float dd = edist[e];
  float inv = 1.0f / dd;
  float th = dd * (PI_F / CUT);
  float s1 = sinf(th), c1 = cosf(th);
  float fc = (dd < CUT) ? 0.5f * (c1 + 1.0f) : 0.0f;
  float* g = geo + (size_t)p * 24;
  float twoc = 2.0f * c1;
  float skp = 0.0f, sk = s1;
  #pragma unroll
  for (int k = 0; k < E_RBF; k++) {
    g[k] = sk * inv * fc;
    float nx = twoc * sk - skp;
    skp = sk; sk = nx;
  }
  g[20] = ediff[3 * (size_t)e] * inv;
  g[21] = ediff[3 * (size_t)e + 1] * inv;
  g[22] = ediff[3 * (size_t)e + 2] * inv;
  g[23] = fc;
}

// ---------------- device helpers for weight packing ----------------
__device__ __forceinline__ void pack_w_item(
    const float* __restrict__ Wu, const float* __restrict__ Wv,
    bf16* __restrict__ wp, int t) {
  int lane = t & 63;
  int c    = (t >> 6) & 7;
  int kb   = (t >> 9) & 3;
  int mat  = (t >> 11) & 1;
  int l    = t >> 12;
  const float* src = (mat ? Wv : Wu) + (size_t)l * H * H;
  bf16* dst = wp + ((size_t)(l * 2 + mat) * 16384) + (((kb * 8 + c) * 64 + lane) * 8);
  int quad = lane >> 4;
  int n = c * 16 + (lane & 15);
  #pragma unroll
  for (int j = 0; j < 8; j++) {
    int k = kb * 32 + quad * 8 + j;
    dst[j] = __float2bfloat16(src[(size_t)k * H + n]);
  }
}

__device__ __forceinline__ void pack_b_item(
    const float* __restrict__ src, bf16* __restrict__ dst,
    int K, int ncols, int t) {
  int kblocks = K >> 5, ncols16 = ncols >> 4;
  int lane = t & 63;
  int idx = t >> 6;
  int c = idx % ncols16; idx /= ncols16;
  int kb = idx % kblocks; idx /= kblocks;
  int l = idx;
  const float* s = src + (size_t)l * K * ncols;
  bf16* d = dst + (size_t)l * K * ncols + (((kb * ncols16 + c) * 64 + lane) * 8);
  int quad = lane >> 4;
  int n = c * 16 + (lane & 15);
  #pragma unroll
  for (int j = 0; j < 8; j++) {
    int k = kb * 32 + quad * 8 + j;
    d[j] = __float2bfloat16(s[(size_t)k * ncols + n]);
  }
}

// ---------------- one-shot setup: all weight packs + node_init + cnt zero ----------------
__global__ __launch_bounds__(256) void pack_all(
    const float* __restrict__ Wu, const float* __restrict__ Wv, bf16* __restrict__ wpack,
    const float* __restrict__ uw1, bf16* __restrict__ wp_m1,
    const float* __restrict__ uw2, bf16* __restrict__ wp_m2,
    const float* __restrict__ mw1, bf16* __restrict__ wp_sm1,
    const float* __restrict__ mw2, bf16* __restrict__ wp_sm2,
    const float* __restrict__ rw1, bf16* __restrict__ wp_ro1,
    const float* __restrict__ rw2, bf16* __restrict__ wp_ro2,
    const int* __restrict__ z, const float* __restrict__ embed,
    float* __restrict__ ns, bf16* __restrict__ ns16,
    int* __restrict__ cnt, int N) {
  const int T0 = 12288;            // pack_w (UV)
  const int T1 = T0 + 12288;       // uw1 K=256 n=128 L=3
  const int T2 = T1 + 18432;       // uw2 K=128 n=384 L=3
  const int T3 = T2 + 6144;        // mw1 K=128 n=128 L=3
  const int T4 = T3 + 18432;       // mw2 K=128 n=384 L=3
  const int T5 = T4 + 2048;        // rw1
  const int T6 = T5 + 2048;        // rw2
  const int TN = T6 + N * H;       // node_init
  const int TT = TN + N;           // cnt zero
  for (int t = blockIdx.x * blockDim.x + threadIdx.x; t < TT; t += gridDim.x * blockDim.x) {
    if (t < T0)      pack_w_item(Wu, Wv, wpack, t);
    else if (t < T1) pack_b_item(uw1, wp_m1, 256, 128, t - T0);
    else if (t < T2) pack_b_item(uw2, wp_m2, 128, 384, t - T1);
    else if (t < T3) pack_b_item(mw1, wp_sm1, 128, 128, t - T2);
    else if (t < T4) pack_b_item(mw2, wp_sm2, 128, 384, t - T3);
    else if (t < T5) pack_b_item(rw1, wp_ro1, 128, 128, t - T4);
    else if (t < T6) pack_b_item(rw2, wp_ro2, 128, 128, t - T5);
    else if (t < TN) {
      int u = t - T6;
      int i = u >> 7, h = u & 127;
      float v = embed[(size_t)z[i] * H + h];
      ns[(size_t)i * H + h] = v;
      ns16[(size_t)i * H + h] = __float2bfloat16(v);
    } else {
      cnt[t - TN] = 0;
    }
  }
}

// ---------------- fused 2-stage MLP (layer-0 only): so = (silu(A@W1+b1))@W2+b2 ----------------
__global__ __launch_bounds__(256) void mlp_msg(
    const bf16* __restrict__ A, const bf16* __restrict__ Wp1,
    const float* __restrict__ b1, const bf16* __restrict__ Wp2,
    const float* __restrict__ b2, bf16* __restrict__ so, int M) {
  __shared__ bf16 m1l[32][136];
  int wave = threadIdx.x >> 6, lane = threadIdx.x & 63;
  int rowg = wave >> 1, ch = wave & 1;
  int r0 = blockIdx.x * 32 + rowg * 16;
  int quad = lane >> 4, nn = lane & 15;
  int arow = r0 + nn; if (arow >= M) arow = M - 1;
  f32x4 acc[4] = {};
  for (int kb = 0; kb < 4; kb++) {
    bf16x8 af = *(const bf16x8*)&A[(size_t)arow * H + kb * 32 + quad * 8];
    #pragma unroll
    for (int c = 0; c < 4; c++) {
      int cg = ch * 4 + c;
      bf16x8 bw = *(const bf16x8*)&Wp1[(((kb * 8 + cg) * 64) + lane) * 8];
      acc[c] = __builtin_amdgcn_mfma_f32_16x16x32_bf16(af, bw, acc[c], 0, 0, 0);
    }
  }
  #pragma unroll
  for (int c = 0; c < 4; c++) {
    int n = (ch * 4 + c) * 16 + nn;
    float bb = b1[n];
    #pragma unroll
    for (int r = 0; r < 4; r++) {
      int lr = rowg * 16 + quad * 4 + r;
      m1l[lr][n] = __float2bfloat16(silu_f(acc[c][r] + bb));
    }
  }
  __syncthreads();
  f32x4 a0[4] = {}, a1[4] = {}, a2[4] = {};
  for (int kb = 0; kb < 4; kb++) {
    bf16x8 af = *(const bf16x8*)&m1l[rowg * 16 + nn][kb * 32 + quad * 8];
    #pragma unroll
    for (int c = 0; c < 4; c++) {
      int cg = ch * 4 + c;
      bf16x8 b0 = *(const bf16x8*)&Wp2[(((kb * 24 + cg) * 64) + lane) * 8];
      bf16x8 b1v = *(const bf16x8*)&Wp2[(((kb * 24 + cg + 8) * 64) + lane) * 8];
      bf16x8 b2v = *(const bf16x8*)&Wp2[(((kb * 24 + cg + 16) * 64) + lane) * 8];
      a0[c] = __builtin_amdgcn_mfma_f32_16x16x32_bf16(af, b0, a0[c], 0, 0, 0);
      a1[c] = __builtin_amdgcn_mfma_f32_16x16x32_bf16(af, b1v, a1[c], 0, 0, 0);
      a2[c] = __builtin_amdgcn_mfma_f32_16x16x32_bf16(af, b2v, a2[c], 0, 0, 0);
    }
  }
  #pragma unroll
  for (int c = 0; c < 4; c++) {
    int n = (ch * 4 + c) * 16 + nn;
    float bb0 = b2[n], bb1 = b2[H + n], bb2 = b2[2 * H + n];
    #pragma unroll
    for (int r = 0; r < 4; r++) {
      int row = r0 + quad * 4 + r;
      if (row < M) {
        so[(size_t)row * F3H + n]           = __float2bfloat16(a0[c][r] + bb0);
        so[(size_t)row * F3H + H + n]       = __float2bfloat16(a1[c][r] + bb1);
        so[(size_t)row * F3H + 2 * H + n]   = __float2bfloat16(a2[c][r] + bb2);
      }
    }
  }
}

// ---------------- fused UV dual-GEMM + vnorm + update-MLP + epilogue + next-stage MLP ----
// 16 nodes (48 UV rows) per block, 6 waves, LDS 58 KB -> 2 blocks/CU.
// MODE 0: appends next layer's message-MLP (so out). MODE 1: appends readout (out).
// ns16 of this block's nodes is block-local: phase 4 stores it into vn_l (dead
// after phase 3) instead of global; phases 5/6 consume it. Per-output MFMA/bias
// /silu chains identical to the standalone kernels -> bitwise-same results.
template<int MODE>
__global__ __launch_bounds__(384, 3) void uv_upd(
    const bf16* __restrict__ A, const bf16* __restrict__ Wpuv,
    const float* __restrict__ bu, const float* __restrict__ bv,
    const bf16* __restrict__ nsmsg,
    const bf16* __restrict__ Wp1, const float* __restrict__ b1,
    const bf16* __restrict__ Wp2, const float* __restrict__ b2,
    float* __restrict__ ns,
    float* __restrict__ nv, bf16* __restrict__ nvb16,
    const bf16* __restrict__ Wx1, const float* __restrict__ bx1,
    const bf16* __restrict__ Wx2, const float* __restrict__ bx2,
    bf16* __restrict__ so, float* __restrict__ out, int N) {
  __shared__ float Uv_l[48][132];
  __shared__ float Vv_l[48][132];
  __shared__ bf16 vn_l[16][136];   // phase 2-3: vnorm; phase 4+: ns16 of this tile
  __shared__ bf16 m1l[16][136];
  int wave = threadIdx.x >> 6;     // 0..5
  int lane = threadIdx.x & 63;
  int quad = lane >> 4, nn = lane & 15;
  int M3 = 3 * N;

  // ---- phase 1: dual GEMM; waves 0-2 -> U rows, waves 3-5 -> V rows ----
  {
    int wt = (wave >= 3) ? wave - 3 : wave;
    bool isV = wave >= 3;
    int r0 = blockIdx.x * 48 + wt * 16;
    int arow = r0 + nn; if (arow >= M3) arow = M3 - 1;
    const bf16* Wb = Wpuv + (isV ? 16384 : 0);
    f32x4 acc[8] = {};
    for (int kb = 0; kb < 4; kb++) {
      bf16x8 af = *(const bf16x8*)&A[(size_t)arow * H + kb * 32 + quad * 8];
      #pragma unroll
      for (int c = 0; c < 8; c++) {
        bf16x8 bw = *(const bf16x8*)&Wb[(((kb * 8 + c) * 64) + lane) * 8];
        acc[c] = __builtin_amdgcn_mfma_f32_16x16x32_bf16(af, bw, acc[c], 0, 0, 0);
      }
    }
    const float* bias = isV ? bv : bu;
    #pragma unroll
    for (int c = 0; c < 8; c++) {
      int n = c * 16 + nn;
      float bb = bias[n];
      #pragma unroll
      for (int r = 0; r < 4; r++) {
        int lr = wt * 16 + quad * 4 + r;
        if (isV) Vv_l[lr][n] = acc[c][r] + bb;
        else     Uv_l[lr][n] = acc[c][r] + bb;
      }
    }
  }
  __syncthreads();

  // ---- phase 2: vnorm -> vn_l ----
  for (int t = threadIdx.x; t < 16 * H; t += 384) {
    int node = t >> 7, hh = t & 127;
    float v0 = Vv_l[node * 3][hh];
    float v1 = Vv_l[node * 3 + 1][hh];
    float v2 = Vv_l[node * 3 + 2][hh];
    vn_l[node][hh] = __float2bfloat16(sqrtf(v0 * v0 + v1 * v1 + v2 * v2));
  }
  __syncthreads();

  // ---- phase 3: update-MLP stage 1, K=256; n-groups striped over waves ----
  int r0n = blockIdx.x * 16;
  int arown = r0n + nn; if (arown >= N) arown = N - 1;
  for (int g = wave; g < 8; g += 6) {
    f32x4 acc = {};
    for (int kb = 0; kb < 8; kb++) {
      bf16x8 af;
      if (kb < 4) af = *(const bf16x8*)&vn_l[nn][kb * 32 + quad * 8];
      else        af = *(const bf16x8*)&nsmsg[(size_t)arown * H + (kb - 4) * 32 + quad * 8];
      bf16x8 bw = *(const bf16x8*)&Wp1[(((kb * 8 + g) * 64) + lane) * 8];
      acc = __builtin_amdgcn_mfma_f32_16x16x32_bf16(af, bw, acc, 0, 0, 0);
    }
    int n = g * 16 + nn;
    float bb = b1[n];
    #pragma unroll
    for (int r = 0; r < 4; r++) {
      m1l[quad * 4 + r][n] = __float2bfloat16(silu_f(acc[r] + bb));
    }
  }
  __syncthreads();

  // ---- phase 4: update-MLP stage 2 + gating epilogue; ns16 -> vn_l (LDS) ----
  for (int g = wave; g < 8; g += 6) {
    f32x4 aav = {}, aas = {}, asz = {};
    for (int kb = 0; kb < 4; kb++) {
      bf16x8 af = *(const bf16x8*)&m1l[nn][kb * 32 + quad * 8];
      bf16x8 b0 = *(const bf16x8*)&Wp2[(((kb * 24 + g) * 64) + lane) * 8];
      bf16x8 b1v = *(const bf16x8*)&Wp2[(((kb * 24 + g + 8) * 64) + lane) * 8];
      bf16x8 b2v = *(const bf16x8*)&Wp2[(((kb * 24 + g + 16) * 64) + lane) * 8];
      aav = __builtin_amdgcn_mfma_f32_16x16x32_bf16(af, b0, aav, 0, 0, 0);
      aas = __builtin_amdgcn_mfma_f32_16x16x32_bf16(af, b1v, aas, 0, 0, 0);
      asz = __builtin_amdgcn_mfma_f32_16x16x32_bf16(af, b2v, asz, 0, 0, 0);
    }
    int n = g * 16 + nn;
    float bav = b2[n], bas = b2[H + n], bss = b2[2 * H + n];
    #pragma unroll
    for (int r = 0; r < 4; r++) {
      int row = r0n + quad * 4 + r;
      if (row < N) {
        int lrn = quad * 4 + r;
        float avv = aav[r] + bav;
        float asv = aas[r] + bas;
        float ass = asz[r] + bss;
        float u0 = Uv_l[lrn * 3 + 0][n];
        float u1 = Uv_l[lrn * 3 + 1][n];
        float u2 = Uv_l[lrn * 3 + 2][n];
        float v0 = Vv_l[lrn * 3 + 0][n];
        float v1 = Vv_l[lrn * 3 + 1][n];
        float v2 = Vv_l[lrn * 3 + 2][n];
        float dot = u0 * v0 + u1 * v1 + u2 * v2;
        float ns_new = ns[(size_t)row * H + n] + asv * dot + ass;
        ns[(size_t)row * H + n] = ns_new;
        vn_l[lrn][n] = __float2bfloat16(ns_new);   // ns16, block-local
        float n0 = nv[(size_t)(3 * row + 0) * H + n] + avv * u0;
        float n1 = nv[(size_t)(3 * row + 1) * H + n] + avv * u1;
        float n2 = nv[(size_t)(3 * row + 2) * H + n] + avv * u2;
        nv[(size_t)(3 * row + 0) * H + n] = n0;
        nv[(size_t)(3 * row + 1) * H + n] = n1;
        nv[(size_t)(3 * row + 2) * H + n] = n2;
        nvb16[(size_t)(3 * row + 0) * H + n] = __float2bfloat16(n0);
        nvb16[(size_t)(3 * row + 1) * H + n] = __float2bfloat16(n1);
        nvb16[(size_t)(3 * row + 2) * H + n] = __float2bfloat16(n2);
      }
    }
  }
  __syncthreads();

  // ---- phase 5: next-stage MLP stage 1 (K=128, A = ns16 in vn_l) ----
  for (int g = wave; g < 8; g += 6) {
    f32x4 acc = {};
    for (int kb = 0; kb < 4; kb++) {
      bf16x8 af = *(const bf16x8*)&vn_l[nn][kb * 32 + quad * 8];
      bf16x8 bw = *(const bf16x8*)&Wx1[(((kb * 8 + g) * 64) + lane) * 8];
      acc = __builtin_amdgcn_mfma_f32_16x16x32_bf16(af, bw, acc, 0, 0, 0);
    }
    int n = g * 16 + nn;
    float bb = bx1[n];
    #pragma unroll
    for (int r = 0; r < 4; r++) {
      m1l[quad * 4 + r][n] = __float2bfloat16(silu_f(acc[r] + bb));
    }
  }
  __syncthreads();

  // ---- phase 6: next-stage MLP stage 2 ----
  if (MODE == 0) {
    // message-MLP of next layer -> so (384 cols)
    for (int g = wave; g < 8; g += 6) {
      f32x4 a0 = {}, a1 = {}, a2 = {};
      for (int kb = 0; kb < 4; kb++) {
        bf16x8 af = *(const bf16x8*)&m1l[nn][kb * 32 + quad * 8];
        bf16x8 b0 = *(const bf16x8*)&Wx2[(((kb * 24 + g) * 64) + lane) * 8];
        bf16x8 b1v = *(const bf16x8*)&Wx2[(((kb * 24 + g + 8) * 64) + lane) * 8];
        bf16x8 b2v = *(const bf16x8*)&Wx2[(((kb * 24 + g + 16) * 64) + lane) * 8];
        a0 = __builtin_amdgcn_mfma_f32_16x16x32_bf16(af, b0, a0, 0, 0, 0);
        a1 = __builtin_amdgcn_mfma_f32_16x16x32_bf16(af, b1v, a1, 0, 0, 0);
        a2 = __builtin_amdgcn_mfma_f32_16x16x32_bf16(af, b2v, a2, 0, 0, 0);
      }
      int n = g * 16 + nn;
      float bb0 = bx2[n], bb1 = bx2[H + n], bb2 = bx2[2 * H + n];
      #pragma unroll
      for (int r = 0; r < 4; r++) {
        int row = r0n + quad * 4 + r;
        if (row < N) {
          so[(size_t)row * F3H + n]         = __float2bfloat16(a0[r] + bb0);
          so[(size_t)row * F3H + H + n]     = __float2bfloat16(a1[r] + bb1);
          so[(size_t)row * F3H + 2 * H + n] = __float2bfloat16(a2[r] + bb2);
        }
      }
    }
  } else {
    // readout stage 2 -> out fp32 (128 cols)
    for (int g = wave; g < 8; g += 6) {
      f32x4 acc = {};
      for (int kb = 0; kb < 4; kb++) {
        bf16x8 af = *(const bf16x8*)&m1l[nn][kb * 32 + quad * 8];
        bf16x8 bw = *(const bf16x8*)&Wx2[(((kb * 8 + g) * 64) + lane) * 8];
        acc = __builtin_amdgcn_mfma_f32_16x16x32_bf16(af, bw, acc, 0, 0, 0);
      }
      int n = g * 16 + nn;
      float bb = bx2[n];
      #pragma unroll
      for (int r = 0; r < 4; r++) {
        int row = r0n + quad * 4 + r;
        if (row < N) out[(size_t)row * H + n] = acc[r] + bb;
      }
    }
  }
}

// ---------------- message: round-0 structure, edge loop unrolled x2 ----------------
// At the measured random-gather ceiling (~2.15 TB/s effective, invariant under
// r1-r4 restructures). Do not restructure further.
template<bool HASNV>
__global__ __launch_bounds__(128, 4) void message3(
    const int* __restrict__ srcs, const int* __restrict__ rowstart,
    const int* __restrict__ cnt, const float* __restrict__ geo,
    const float* __restrict__ Wf, const float* __restrict__ bfb,
    const bf16* __restrict__ so, const bf16* __restrict__ nvb16,
    const float* __restrict__ nvA,
    float* __restrict__ ns, float* __restrict__ nvB,
    bf16* __restrict__ nvmsg16, bf16* __restrict__ nsmsg, int N) {
  int i = blockIdx.x;
  int h = threadIdx.x;

  float wf0[E_RBF], wf1[E_RBF], wf2[E_RBF];
  #pragma unroll
  for (int k = 0; k < E_RBF; k++) {
    wf0[k] = Wf[k * F3H + h];
    wf1[k] = Wf[k * F3H + H + h];
    wf2[k] = Wf[k * F3H + 2 * H + h];
  }
  float bb0 = bfb[h], bb1 = bfb[H + h], bb2 = bfb[2 * H + h];

  float accs = 0.0f, a0 = 0.0f, a1 = 0.0f, a2 = 0.0f;
  int jlo = rowstart[i], jhi = jlo + cnt[i];
  int j = jlo;
  for (; j + 1 < jhi; j += 2) {
    int s0 = srcs[j];
    int s1 = srcs[j + 1];
    const bf16* sop0 = so + (size_t)s0 * F3H;
    const bf16* sop1 = so + (size_t)s1 * F3H;
    float sA0 = b2f(sop0[h]), sB0 = b2f(sop0[H + h]), sC0 = b2f(sop0[2 * H + h]);
    float sA1 = b2f(sop1[h]), sB1 = b2f(sop1[H + h]), sC1 = b2f(sop1[2 * H + h]);
    float nA0, nB0, nC0, nA1, nB1, nC1;
    if (HASNV) {
      const bf16* nvp0 = nvb16 + (size_t)s0 * F3H;
      const bf16* nvp1 = nvb16 + (size_t)s1 * F3H;
      nA0 = b2f(nvp0[h]); nB0 = b2f(nvp0[H + h]); nC0 = b2f(nvp0[2 * H + h]);
      nA1 = b2f(nvp1[h]); nB1 = b2f(nvp1[H + h]); nC1 = b2f(nvp1[2 * H + h]);
    }

    {
      const float* g = geo + (size_t)j * 24;
      float gg[24];
      #pragma unroll
      for (int q = 0; q < 6; q++) *(float4*)&gg[4 * q] = *(const float4*)&g[4 * q];
      float fc = gg[23];
      float f0 = bb0 * fc, f1 = bb1 * fc, f2 = bb2 * fc;
      #pragma unroll
      for (int k = 0; k < E_RBF; k++) {
        float rk = gg[k];
        f0 += rk * wf0[k];
        f1 += rk * wf1[k];
        f2 += rk * wf2[k];
      }
      float u0 = gg[20], u1 = gg[21], u2 = gg[22];
      float gsv = f0 * sA0;
      float gev = f1 * sB0;
      accs += f2 * sC0;
      if (HASNV) {
        a0 += nA0 * gsv + gev * u0;
        a1 += nB0 * gsv + gev * u1;
        a2 += nC0 * gsv + gev * u2;
      } else {
        a0 += gev * u0;
        a1 += gev * u1;
        a2 += gev * u2;
      }
    }
    {
      const float* g = geo + (size_t)(j + 1) * 24;
      float gg[24];
      #pragma unroll
      for (int q = 0; q < 6; q++) *(float4*)&gg[4 * q] = *(const float4*)&g[4 * q];
      float fc = gg[23];
      float f0 = bb0 * fc, f1 = bb1 * fc, f2 = bb2 * fc;
      #pragma unroll
      for (int k = 0; k < E_RBF; k++) {
        float rk = gg[k];
        f0 += rk * wf0[k];
        f1 += rk * wf1[k];
        f2 += rk * wf2[k];
      }
      float u0 = gg[20], u1 = gg[21], u2 = gg[22];
      float gsv = f0 * sA1;
      float gev = f1 * sB1;
      accs += f2 * sC1;
      if (HASNV) {
        a0 += nA1 * gsv + gev * u0;
        a1 += nB1 * gsv + gev * u1;
        a2 += nC1 * gsv + gev * u2;
      } else {
        a0 += gev * u0;
        a1 += gev * u1;
        a2 += gev * u2;
      }
    }
  }
  if (j < jhi) {
    int src = srcs[j];
    const float* g = geo + (size_t)j * 24;
    float gg[24];
    #pragma unroll
    for (int q = 0; q < 6; q++) *(float4*)&gg[4 * q] = *(const float4*)&g[4 * q];
    float fc = gg[23];
    float f0 = bb0 * fc, f1 = bb1 * fc, f2 = bb2 * fc;
    #pragma unroll
    for (int k = 0; k < E_RBF; k++) {
      float rk = gg[k];
      f0 += rk * wf0[k];
      f1 += rk * wf1[k];
      f2 += rk * wf2[k];
    }
    float u0 = gg[20], u1 = gg[21], u2 = gg[22];
    const bf16* sop = so + (size_t)src * F3H;
    float gsv = f0 * b2f(sop[h]);
    float gev = f1 * b2f(sop[H + h]);
    accs += f2 * b2f(sop[2 * H + h]);
    if (HASNV) {
      const bf16* nvp = nvb16 + (size_t)src * F3H;
      a0 += b2f(nvp[h])         * gsv + gev * u0;
      a1 += b2f(nvp[H + h])     * gsv + gev * u1;
      a2 += b2f(nvp[2 * H + h]) * gsv + gev * u2;
    } else {
      a0 += gev * u0;
      a1 += gev * u1;
      a2 += gev * u2;
    }
  }

  float ns_new = ns[(size_t)i * H + h] + accs;
  ns[(size_t)i * H + h] = ns_new;
  nsmsg[(size_t)i * H + h] = __float2bfloat16(ns_new);
  float o0, o1, o2;
  if (HASNV) {
    const float* nvi = nvA + (size_t)i * F3H;
    o0 = nvi[h] + a0;
    o1 = nvi[H + h] + a1;
    o2 = nvi[2 * H + h] + a2;
  } else {
    o0 = a0; o1 = a1; o2 = a2;
  }
  nvB[(size_t)i * F3H + h]         = o0;
  nvB[(size_t)i * F3H + H + h]     = o1;
  nvB[(size_t)i * F3H + 2 * H + h] = o2;
  nvmsg16[(size_t)i * F3H + h]         = __float2bfloat16(o0);
  nvmsg16[(size_t)i * F3H + H + h]     = __float2bfloat16(o1);
  nvmsg16[(size_t)i * F3H + 2 * H + h] = __float2bfloat16(o2);
}

extern "C" void kernel_launch(void* const* d_in, const int* in_sizes, int n_in,
                              void* d_out, int out_size, void* d_ws, size_t ws_size,
                              hipStream_t stream) {
  const int*   z     = (const int*)d_in[0];
  const int*   edge  = (const int*)d_in[1];
  const float* ediff = (const float*)d_in[2];
  const float* edist = (const float*)d_in[3];
  const float* embed = (const float*)d_in[4];
  const float* mfw   = (const float*)d_in[5];
  const float* mfb   = (const float*)d_in[6];
  const float* mw1   = (const float*)d_in[7];
  const float* mb1   = (const float*)d_in[8];
  const float* mw2   = (const float*)d_in[9];
  const float* mb2   = (const float*)d_in[10];
  const float* uUw   = (const float*)d_in[11];
  const float* uUb   = (const float*)d_in[12];
  const float* uVw   = (const float*)d_in[13];
  const float* uVb   = (const float*)d_in[14];
  const float* uw1   = (const float*)d_in[15];
  const float* ub1   = (const float*)d_in[16];
  const float* uw2   = (const float*)d_in[17];
  const float* ub2   = (const float*)d_in[18];
  const float* rw1   = (const float*)d_in[19];
  const float* rb1   = (const float*)d_in[20];
  const float* rw2   = (const float*)d_in[21];
  const float* rb2   = (const float*)d_in[22];

  const int N  = in_sizes[0];   // 10000
  const int nE = in_sizes[3];   // 160000

  float* ws = (float*)d_ws;
  size_t off = 0;
  float* ns      = ws + off; off += (size_t)N * H;
  float* nvA     = ws + off; off += (size_t)N * F3H;
  float* nvB     = ws + off; off += (size_t)N * F3H;
  float* geo     = ws + off; off += (size_t)nE * 24;
  bf16* so       = (bf16*)(ws + off); off += (size_t)N * F3H / 2;
  bf16* nvb16    = (bf16*)(ws + off); off += (size_t)N * F3H / 2;
  bf16* nvmsg16  = (bf16*)(ws + off); off += (size_t)N * F3H / 2;
  bf16* nsmsg    = (bf16*)(ws + off); off += (size_t)N * 64;        // N*128 bf16
  bf16* ns16     = (bf16*)(ws + off); off += (size_t)N * 64;        // N*128 bf16 (l0 only)
  bf16* wpack    = (bf16*)(ws + off); off += 3 * 2 * 16384 / 2;     // UV
  bf16* wp_m1    = (bf16*)(ws + off); off += 3 * 256 * 128 / 2;
  bf16* wp_m2    = (bf16*)(ws + off); off += 3 * 128 * 384 / 2;
  bf16* wp_sm1   = (bf16*)(ws + off); off += 3 * 128 * 128 / 2;
  bf16* wp_sm2   = (bf16*)(ws + off); off += 3 * 128 * 384 / 2;
  bf16* wp_ro1   = (bf16*)(ws + off); off += 128 * 128 / 2;
  bf16* wp_ro2   = (bf16*)(ws + off); off += 128 * 128 / 2;
  int* srcs     = (int*)(ws + off); off += nE;
  int* cnt      = (int*)(ws + off); off += N;
  int* rowstart = (int*)(ws + off); off += N;
  int* cur      = (int*)(ws + off); off += N;

  const int tilesN = (N + 31) / 32;            // 313
  const int tilesUV = (N + 15) / 16;           // 625

  pack_all<<<1024, 256, 0, stream>>>(
      uUw, uVw, wpack, uw1, wp_m1, uw2, wp_m2, mw1, wp_sm1, mw2, wp_sm2,
      rw1, wp_ro1, rw2, wp_ro2, z, embed, ns, ns16, cnt, N);
  csr_hist<<<(nE + 255) / 256, 256, 0, stream>>>(edge, cnt, nE);
  csr_scan<<<1, 1024, 0, stream>>>(cnt, rowstart, cur, N);
  csr_fill_pack<<<(nE + 255) / 256, 256, 0, stream>>>(edge, cur, edist, ediff, srcs, geo, nE);

  float* nv_cur = nvA;
  float* nv_nxt = nvB;
  for (int l = 0; l < NLAYER; l++) {
    if (l == 0)
      mlp_msg<<<tilesN, 256, 0, stream>>>(
          ns16, wp_sm1, mb1, wp_sm2, mb2, so, N);

    if (l == 0)
      message3<false><<<N, H, 0, stream>>>(srcs, rowstart, cnt, geo,
                                           mfw + (size_t)l * E_RBF * F3H, mfb + (size_t)l * F3H,
                                           so, nvb16, nv_cur, ns, nv_nxt, nvmsg16, nsmsg, N);
    else
      message3<true><<<N, H, 0, stream>>>(srcs, rowstart, cnt, geo,
                                          mfw + (size_t)l * E_RBF * F3H, mfb + (size_t)l * F3H,
                                          so, nvb16, nv_cur, ns, nv_nxt, nvmsg16, nsmsg, N);

    if (l < NLAYER - 1) {
      uv_upd<0><<<tilesUV, 384, 0, stream>>>(
          nvmsg16, wpack + (size_t)l * 2 * 16384,
          uUb + (size_t)l * H, uVb + (size_t)l * H,
          nsmsg,
          wp_m1 + (size_t)l * 256 * 128, ub1 + (size_t)l * H,
          wp_m2 + (size_t)l * 128 * 384, ub2 + (size_t)l * F3H,
          ns, nv_nxt, nvb16,
          wp_sm1 + (size_t)(l + 1) * 128 * 128, mb1 + (size_t)(l + 1) * H,
          wp_sm2 + (size_t)(l + 1) * 128 * 384, mb2 + (size_t)(l + 1) * F3H,
          so, nullptr, N);
    } else {
      uv_upd<1><<<tilesUV, 384, 0, stream>>>(
          nvmsg16, wpack + (size_t)l * 2 * 16384,
          uUb + (size_t)l * H, uVb + (size_t)l * H,
          nsmsg,
          wp_m1 + (size_t)l * 256 * 128, ub1 + (size_t)l * H,
          wp_m2 + (size_t)l * 128 * 384, ub2 + (size_t)l * F3H,
          ns, nv_nxt, nvb16,
          wp_ro1, rb1, wp_ro2, rb2,
          nullptr, (float*)d_out, N);
    }

    float* t = nv_cur; nv_cur = nv_nxt; nv_nxt = t;
  }
}

// Round 10
// 415.268 us; speedup vs baseline: 1.1104x; 1.1104x over previous
//
#include <hip/hip_runtime.h>
#include <hip/hip_bf16.h>

typedef __hip_bfloat16 bf16;
typedef __attribute__((ext_vector_type(8))) short bf16x8;
typedef __attribute__((ext_vector_type(4))) float f32x4;

#define H 128
#define F3H 384
#define E_RBF 20
#define NLAYER 3

__device__ __forceinline__ float silu_f(float x) { return x / (1.0f + __expf(-x)); }
__device__ __forceinline__ float b2f(bf16 x) { return __bfloat162float(x); }

constexpr float PI_F = 3.14159265358979323846f;
constexpr float CUT = 5.0f;

// ---------------- CSR hist ----------------
__global__ __launch_bounds__(256) void csr_hist(
    const int* __restrict__ edge, int* __restrict__ cnt, int nE) {
  int e = blockIdx.x * blockDim.x + threadIdx.x;
  if (e < nE) atomicAdd(&cnt[edge[2 * e]], 1);
}

// ---------------- CSR scan: 1024-thread LDS tree scan ----------------
__global__ __launch_bounds__(1024) void csr_scan(
    const int* __restrict__ cnt, int* __restrict__ rowstart, int* __restrict__ cur, int N) {
  __shared__ int part[1024];
  int t = threadIdx.x;
  int chunk = (N + 1023) / 1024;
  int lo = t * chunk; if (lo > N) lo = N;
  int hi = lo + chunk; if (hi > N) hi = N;
  int s = 0;
  for (int i = lo; i < hi; i++) s += cnt[i];
  part[t] = s;
  __syncthreads();
  for (int off = 1; off < 1024; off <<= 1) {
    int v = (t >= off) ? part[t - off] : 0;
    __syncthreads();
    part[t] += v;
    __syncthreads();
  }
  int r = (t == 0) ? 0 : part[t - 1];
  for (int i = lo; i < hi; i++) { rowstart[i] = r; cur[i] = r; r += cnt[i]; }
}

// ---------------- CSR fill + edge geometry pack (fused; no elist) ----------------
__global__ __launch_bounds__(256) void csr_fill_pack(
    const int* __restrict__ edge, int* __restrict__ cur,
    const float* __restrict__ edist, const float* __restrict__ ediff,
    int* __restrict__ srcs, float* __restrict__ geo, int nE) {
  int e = blockIdx.x * blockDim.x + threadIdx.x;
  if (e >= nE) return;
  int d = edge[2 * e];
  int p = atomicAdd(&cur[d], 1);
  srcs[p] = edge[2 * e + 1];
  float dd = edist[e];
  float inv = 1.0f / dd;
  float th = dd * (PI_F / CUT);
  float s1 = sinf(th), c1 = cosf(th);
  float fc = (dd < CUT) ? 0.5f * (c1 + 1.0f) : 0.0f;
  float* g = geo + (size_t)p * 24;
  float twoc = 2.0f * c1;
  float skp = 0.0f, sk = s1;
  #pragma unroll
  for (int k = 0; k < E_RBF; k++) {
    g[k] = sk * inv * fc;
    float nx = twoc * sk - skp;
    skp = sk; sk = nx;
  }
  g[20] = ediff[3 * (size_t)e] * inv;
  g[21] = ediff[3 * (size_t)e + 1] * inv;
  g[22] = ediff[3 * (size_t)e + 2] * inv;
  g[23] = fc;
}

// ---------------- device helpers for weight packing ----------------
__device__ __forceinline__ void pack_w_item(
    const float* __restrict__ Wu, const float* __restrict__ Wv,
    bf16* __restrict__ wp, int t) {
  int lane = t & 63;
  int c    = (t >> 6) & 7;
  int kb   = (t >> 9) & 3;
  int mat  = (t >> 11) & 1;
  int l    = t >> 12;
  const float* src = (mat ? Wv : Wu) + (size_t)l * H * H;
  bf16* dst = wp + ((size_t)(l * 2 + mat) * 16384) + (((kb * 8 + c) * 64 + lane) * 8);
  int quad = lane >> 4;
  int n = c * 16 + (lane & 15);
  #pragma unroll
  for (int j = 0; j < 8; j++) {
    int k = kb * 32 + quad * 8 + j;
    dst[j] = __float2bfloat16(src[(size_t)k * H + n]);
  }
}

__device__ __forceinline__ void pack_b_item(
    const float* __restrict__ src, bf16* __restrict__ dst,
    int K, int ncols, int t) {
  int kblocks = K >> 5, ncols16 = ncols >> 4;
  int lane = t & 63;
  int idx = t >> 6;
  int c = idx % ncols16; idx /= ncols16;
  int kb = idx % kblocks; idx /= kblocks;
  int l = idx;
  const float* s = src + (size_t)l * K * ncols;
  bf16* d = dst + (size_t)l * K * ncols + (((kb * ncols16 + c) * 64 + lane) * 8);
  int quad = lane >> 4;
  int n = c * 16 + (lane & 15);
  #pragma unroll
  for (int j = 0; j < 8; j++) {
    int k = kb * 32 + quad * 8 + j;
    d[j] = __float2bfloat16(s[(size_t)k * ncols + n]);
  }
}

// ---------------- one-shot setup: all weight packs + node_init + cnt zero ----------------
__global__ __launch_bounds__(256) void pack_all(
    const float* __restrict__ Wu, const float* __restrict__ Wv, bf16* __restrict__ wpack,
    const float* __restrict__ uw1, bf16* __restrict__ wp_m1,
    const float* __restrict__ uw2, bf16* __restrict__ wp_m2,
    const float* __restrict__ mw1, bf16* __restrict__ wp_sm1,
    const float* __restrict__ mw2, bf16* __restrict__ wp_sm2,
    const float* __restrict__ rw1, bf16* __restrict__ wp_ro1,
    const float* __restrict__ rw2, bf16* __restrict__ wp_ro2,
    const int* __restrict__ z, const float* __restrict__ embed,
    float* __restrict__ ns, bf16* __restrict__ ns16,
    int* __restrict__ cnt, int N) {
  const int T0 = 12288;            // pack_w (UV)
  const int T1 = T0 + 12288;       // uw1 K=256 n=128 L=3
  const int T2 = T1 + 18432;       // uw2 K=128 n=384 L=3
  const int T3 = T2 + 6144;        // mw1 K=128 n=128 L=3
  const int T4 = T3 + 18432;       // mw2 K=128 n=384 L=3
  const int T5 = T4 + 2048;        // rw1
  const int T6 = T5 + 2048;        // rw2
  const int TN = T6 + N * H;       // node_init
  const int TT = TN + N;           // cnt zero
  for (int t = blockIdx.x * blockDim.x + threadIdx.x; t < TT; t += gridDim.x * blockDim.x) {
    if (t < T0)      pack_w_item(Wu, Wv, wpack, t);
    else if (t < T1) pack_b_item(uw1, wp_m1, 256, 128, t - T0);
    else if (t < T2) pack_b_item(uw2, wp_m2, 128, 384, t - T1);
    else if (t < T3) pack_b_item(mw1, wp_sm1, 128, 128, t - T2);
    else if (t < T4) pack_b_item(mw2, wp_sm2, 128, 384, t - T3);
    else if (t < T5) pack_b_item(rw1, wp_ro1, 128, 128, t - T4);
    else if (t < T6) pack_b_item(rw2, wp_ro2, 128, 128, t - T5);
    else if (t < TN) {
      int u = t - T6;
      int i = u >> 7, h = u & 127;
      float v = embed[(size_t)z[i] * H + h];
      ns[(size_t)i * H + h] = v;
      ns16[(size_t)i * H + h] = __float2bfloat16(v);
    } else {
      cnt[t - TN] = 0;
    }
  }
}

// ---------------- fused 2-stage MLP (layer-0 only): so = (silu(A@W1+b1))@W2+b2 ----------------
__global__ __launch_bounds__(256) void mlp_msg(
    const bf16* __restrict__ A, const bf16* __restrict__ Wp1,
    const float* __restrict__ b1, const bf16* __restrict__ Wp2,
    const float* __restrict__ b2, bf16* __restrict__ so, int M) {
  __shared__ bf16 m1l[32][136];
  int wave = threadIdx.x >> 6, lane = threadIdx.x & 63;
  int rowg = wave >> 1, ch = wave & 1;
  int r0 = blockIdx.x * 32 + rowg * 16;
  int quad = lane >> 4, nn = lane & 15;
  int arow = r0 + nn; if (arow >= M) arow = M - 1;
  f32x4 acc[4] = {};
  for (int kb = 0; kb < 4; kb++) {
    bf16x8 af = *(const bf16x8*)&A[(size_t)arow * H + kb * 32 + quad * 8];
    #pragma unroll
    for (int c = 0; c < 4; c++) {
      int cg = ch * 4 + c;
      bf16x8 bw = *(const bf16x8*)&Wp1[(((kb * 8 + cg) * 64) + lane) * 8];
      acc[c] = __builtin_amdgcn_mfma_f32_16x16x32_bf16(af, bw, acc[c], 0, 0, 0);
    }
  }
  #pragma unroll
  for (int c = 0; c < 4; c++) {
    int n = (ch * 4 + c) * 16 + nn;
    float bb = b1[n];
    #pragma unroll
    for (int r = 0; r < 4; r++) {
      int lr = rowg * 16 + quad * 4 + r;
      m1l[lr][n] = __float2bfloat16(silu_f(acc[c][r] + bb));
    }
  }
  __syncthreads();
  f32x4 a0[4] = {}, a1[4] = {}, a2[4] = {};
  for (int kb = 0; kb < 4; kb++) {
    bf16x8 af = *(const bf16x8*)&m1l[rowg * 16 + nn][kb * 32 + quad * 8];
    #pragma unroll
    for (int c = 0; c < 4; c++) {
      int cg = ch * 4 + c;
      bf16x8 b0 = *(const bf16x8*)&Wp2[(((kb * 24 + cg) * 64) + lane) * 8];
      bf16x8 b1v = *(const bf16x8*)&Wp2[(((kb * 24 + cg + 8) * 64) + lane) * 8];
      bf16x8 b2v = *(const bf16x8*)&Wp2[(((kb * 24 + cg + 16) * 64) + lane) * 8];
      a0[c] = __builtin_amdgcn_mfma_f32_16x16x32_bf16(af, b0, a0[c], 0, 0, 0);
      a1[c] = __builtin_amdgcn_mfma_f32_16x16x32_bf16(af, b1v, a1[c], 0, 0, 0);
      a2[c] = __builtin_amdgcn_mfma_f32_16x16x32_bf16(af, b2v, a2[c], 0, 0, 0);
    }
  }
  #pragma unroll
  for (int c = 0; c < 4; c++) {
    int n = (ch * 4 + c) * 16 + nn;
    float bb0 = b2[n], bb1 = b2[H + n], bb2 = b2[2 * H + n];
    #pragma unroll
    for (int r = 0; r < 4; r++) {
      int row = r0 + quad * 4 + r;
      if (row < M) {
        so[(size_t)row * F3H + n]           = __float2bfloat16(a0[c][r] + bb0);
        so[(size_t)row * F3H + H + n]       = __float2bfloat16(a1[c][r] + bb1);
        so[(size_t)row * F3H + 2 * H + n]   = __float2bfloat16(a2[c][r] + bb2);
      }
    }
  }
}

// ---------------- fused UV dual-GEMM + vnorm + update-MLP + epilogue + next-stage MLP ----
// 16 nodes (48 UV rows) per block, 8 waves (512 thr), LDS 58 KB -> 2 blocks/CU.
// BALANCED striping (r9's 6-wave `g += 6` made waves 0-1 do 2x work in every
// MLP phase -> barrier stragglers): phases 3-6 use g = wave exactly (8 groups,
// 8 waves); phase 1 gives each wave column-group cg=wave across all 6 row-tiles
// (3 U + 3 V). Per-output MFMA/bias/silu chains identical -> bitwise-same.
template<int MODE>
__global__ __launch_bounds__(512, 4) void uv_upd(
    const bf16* __restrict__ A, const bf16* __restrict__ Wpuv,
    const float* __restrict__ bu, const float* __restrict__ bv,
    const bf16* __restrict__ nsmsg,
    const bf16* __restrict__ Wp1, const float* __restrict__ b1,
    const bf16* __restrict__ Wp2, const float* __restrict__ b2,
    float* __restrict__ ns,
    float* __restrict__ nv, bf16* __restrict__ nvb16,
    const bf16* __restrict__ Wx1, const float* __restrict__ bx1,
    const bf16* __restrict__ Wx2, const float* __restrict__ bx2,
    bf16* __restrict__ so, float* __restrict__ out, int N) {
  __shared__ float Uv_l[48][132];
  __shared__ float Vv_l[48][132];
  __shared__ bf16 vn_l[16][136];   // phase 2-3: vnorm; phase 4+: ns16 of this tile
  __shared__ bf16 m1l[16][136];
  int wave = threadIdx.x >> 6;     // 0..7
  int lane = threadIdx.x & 63;
  int quad = lane >> 4, nn = lane & 15;
  int M3 = 3 * N;

  // ---- phase 1: dual GEMM; wave = column-group cg, all 6 row-tiles (3 U + 3 V) ----
  {
    int cg = wave;
    f32x4 acc[6] = {};
    #pragma unroll
    for (int t = 0; t < 6; t++) {
      int wt = (t >= 3) ? t - 3 : t;
      const bf16* Wb = Wpuv + ((t >= 3) ? 16384 : 0);
      int r0 = blockIdx.x * 48 + wt * 16;
      int arow = r0 + nn; if (arow >= M3) arow = M3 - 1;
      for (int kb = 0; kb < 4; kb++) {
        bf16x8 af = *(const bf16x8*)&A[(size_t)arow * H + kb * 32 + quad * 8];
        bf16x8 bw = *(const bf16x8*)&Wb[(((kb * 8 + cg) * 64) + lane) * 8];
        acc[t] = __builtin_amdgcn_mfma_f32_16x16x32_bf16(af, bw, acc[t], 0, 0, 0);
      }
    }
    int n = cg * 16 + nn;
    #pragma unroll
    for (int t = 0; t < 6; t++) {
      int wt = (t >= 3) ? t - 3 : t;
      float bb = (t >= 3) ? bv[n] : bu[n];
      #pragma unroll
      for (int r = 0; r < 4; r++) {
        int lr = wt * 16 + quad * 4 + r;
        if (t >= 3) Vv_l[lr][n] = acc[t][r] + bb;
        else        Uv_l[lr][n] = acc[t][r] + bb;
      }
    }
  }
  __syncthreads();

  // ---- phase 2: vnorm -> vn_l ----
  for (int t = threadIdx.x; t < 16 * H; t += 512) {
    int node = t >> 7, hh = t & 127;
    float v0 = Vv_l[node * 3][hh];
    float v1 = Vv_l[node * 3 + 1][hh];
    float v2 = Vv_l[node * 3 + 2][hh];
    vn_l[node][hh] = __float2bfloat16(sqrtf(v0 * v0 + v1 * v1 + v2 * v2));
  }
  __syncthreads();

  // ---- phase 3: update-MLP stage 1, K=256; g = wave (balanced) ----
  int r0n = blockIdx.x * 16;
  int arown = r0n + nn; if (arown >= N) arown = N - 1;
  {
    int g = wave;
    f32x4 acc = {};
    for (int kb = 0; kb < 8; kb++) {
      bf16x8 af;
      if (kb < 4) af = *(const bf16x8*)&vn_l[nn][kb * 32 + quad * 8];
      else        af = *(const bf16x8*)&nsmsg[(size_t)arown * H + (kb - 4) * 32 + quad * 8];
      bf16x8 bw = *(const bf16x8*)&Wp1[(((kb * 8 + g) * 64) + lane) * 8];
      acc = __builtin_amdgcn_mfma_f32_16x16x32_bf16(af, bw, acc, 0, 0, 0);
    }
    int n = g * 16 + nn;
    float bb = b1[n];
    #pragma unroll
    for (int r = 0; r < 4; r++) {
      m1l[quad * 4 + r][n] = __float2bfloat16(silu_f(acc[r] + bb));
    }
  }
  __syncthreads();

  // ---- phase 4: update-MLP stage 2 + gating epilogue; ns16 -> vn_l (LDS) ----
  {
    int g = wave;
    f32x4 aav = {}, aas = {}, asz = {};
    for (int kb = 0; kb < 4; kb++) {
      bf16x8 af = *(const bf16x8*)&m1l[nn][kb * 32 + quad * 8];
      bf16x8 b0 = *(const bf16x8*)&Wp2[(((kb * 24 + g) * 64) + lane) * 8];
      bf16x8 b1v = *(const bf16x8*)&Wp2[(((kb * 24 + g + 8) * 64) + lane) * 8];
      bf16x8 b2v = *(const bf16x8*)&Wp2[(((kb * 24 + g + 16) * 64) + lane) * 8];
      aav = __builtin_amdgcn_mfma_f32_16x16x32_bf16(af, b0, aav, 0, 0, 0);
      aas = __builtin_amdgcn_mfma_f32_16x16x32_bf16(af, b1v, aas, 0, 0, 0);
      asz = __builtin_amdgcn_mfma_f32_16x16x32_bf16(af, b2v, asz, 0, 0, 0);
    }
    int n = g * 16 + nn;
    float bav = b2[n], bas = b2[H + n], bss = b2[2 * H + n];
    #pragma unroll
    for (int r = 0; r < 4; r++) {
      int row = r0n + quad * 4 + r;
      if (row < N) {
        int lrn = quad * 4 + r;
        float avv = aav[r] + bav;
        float asv = aas[r] + bas;
        float ass = asz[r] + bss;
        float u0 = Uv_l[lrn * 3 + 0][n];
        float u1 = Uv_l[lrn * 3 + 1][n];
        float u2 = Uv_l[lrn * 3 + 2][n];
        float v0 = Vv_l[lrn * 3 + 0][n];
        float v1 = Vv_l[lrn * 3 + 1][n];
        float v2 = Vv_l[lrn * 3 + 2][n];
        float dot = u0 * v0 + u1 * v1 + u2 * v2;
        float ns_new = ns[(size_t)row * H + n] + asv * dot + ass;
        ns[(size_t)row * H + n] = ns_new;
        vn_l[lrn][n] = __float2bfloat16(ns_new);   // ns16, block-local
        float n0 = nv[(size_t)(3 * row + 0) * H + n] + avv * u0;
        float n1 = nv[(size_t)(3 * row + 1) * H + n] + avv * u1;
        float n2 = nv[(size_t)(3 * row + 2) * H + n] + avv * u2;
        nv[(size_t)(3 * row + 0) * H + n] = n0;
        nv[(size_t)(3 * row + 1) * H + n] = n1;
        nv[(size_t)(3 * row + 2) * H + n] = n2;
        nvb16[(size_t)(3 * row + 0) * H + n] = __float2bfloat16(n0);
        nvb16[(size_t)(3 * row + 1) * H + n] = __float2bfloat16(n1);
        nvb16[(size_t)(3 * row + 2) * H + n] = __float2bfloat16(n2);
      }
    }
  }
  __syncthreads();

  // ---- phase 5: next-stage MLP stage 1 (K=128, A = ns16 in vn_l); g = wave ----
  {
    int g = wave;
    f32x4 acc = {};
    for (int kb = 0; kb < 4; kb++) {
      bf16x8 af = *(const bf16x8*)&vn_l[nn][kb * 32 + quad * 8];
      bf16x8 bw = *(const bf16x8*)&Wx1[(((kb * 8 + g) * 64) + lane) * 8];
      acc = __builtin_amdgcn_mfma_f32_16x16x32_bf16(af, bw, acc, 0, 0, 0);
    }
    int n = g * 16 + nn;
    float bb = bx1[n];
    #pragma unroll
    for (int r = 0; r < 4; r++) {
      m1l[quad * 4 + r][n] = __float2bfloat16(silu_f(acc[r] + bb));
    }
  }
  __syncthreads();

  // ---- phase 6: next-stage MLP stage 2; g = wave ----
  if (MODE == 0) {
    int g = wave;
    f32x4 a0 = {}, a1 = {}, a2 = {};
    for (int kb = 0; kb < 4; kb++) {
      bf16x8 af = *(const bf16x8*)&m1l[nn][kb * 32 + quad * 8];
      bf16x8 b0 = *(const bf16x8*)&Wx2[(((kb * 24 + g) * 64) + lane) * 8];
      bf16x8 b1v = *(const bf16x8*)&Wx2[(((kb * 24 + g + 8) * 64) + lane) * 8];
      bf16x8 b2v = *(const bf16x8*)&Wx2[(((kb * 24 + g + 16) * 64) + lane) * 8];
      a0 = __builtin_amdgcn_mfma_f32_16x16x32_bf16(af, b0, a0, 0, 0, 0);
      a1 = __builtin_amdgcn_mfma_f32_16x16x32_bf16(af, b1v, a1, 0, 0, 0);
      a2 = __builtin_amdgcn_mfma_f32_16x16x32_bf16(af, b2v, a2, 0, 0, 0);
    }
    int n = g * 16 + nn;
    float bb0 = bx2[n], bb1 = bx2[H + n], bb2 = bx2[2 * H + n];
    #pragma unroll
    for (int r = 0; r < 4; r++) {
      int row = r0n + quad * 4 + r;
      if (row < N) {
        so[(size_t)row * F3H + n]         = __float2bfloat16(a0[r] + bb0);
        so[(size_t)row * F3H + H + n]     = __float2bfloat16(a1[r] + bb1);
        so[(size_t)row * F3H + 2 * H + n] = __float2bfloat16(a2[r] + bb2);
      }
    }
  } else {
    int g = wave;
    f32x4 acc = {};
    for (int kb = 0; kb < 4; kb++) {
      bf16x8 af = *(const bf16x8*)&m1l[nn][kb * 32 + quad * 8];
      bf16x8 bw = *(const bf16x8*)&Wx2[(((kb * 8 + g) * 64) + lane) * 8];
      acc = __builtin_amdgcn_mfma_f32_16x16x32_bf16(af, bw, acc, 0, 0, 0);
    }
    int n = g * 16 + nn;
    float bb = bx2[n];
    #pragma unroll
    for (int r = 0; r < 4; r++) {
      int row = r0n + quad * 4 + r;
      if (row < N) out[(size_t)row * H + n] = acc[r] + bb;
    }
  }
}

// ---------------- message: round-0 structure, edge loop unrolled x2 ----------------
// At the measured random-gather ceiling (~2.15 TB/s effective, invariant under
// r1-r4 restructures). Do not restructure further.
template<bool HASNV>
__global__ __launch_bounds__(128, 4) void message3(
    const int* __restrict__ srcs, const int* __restrict__ rowstart,
    const int* __restrict__ cnt, const float* __restrict__ geo,
    const float* __restrict__ Wf, const float* __restrict__ bfb,
    const bf16* __restrict__ so, const bf16* __restrict__ nvb16,
    const float* __restrict__ nvA,
    float* __restrict__ ns, float* __restrict__ nvB,
    bf16* __restrict__ nvmsg16, bf16* __restrict__ nsmsg, int N) {
  int i = blockIdx.x;
  int h = threadIdx.x;

  float wf0[E_RBF], wf1[E_RBF], wf2[E_RBF];
  #pragma unroll
  for (int k = 0; k < E_RBF; k++) {
    wf0[k] = Wf[k * F3H + h];
    wf1[k] = Wf[k * F3H + H + h];
    wf2[k] = Wf[k * F3H + 2 * H + h];
  }
  float bb0 = bfb[h], bb1 = bfb[H + h], bb2 = bfb[2 * H + h];

  float accs = 0.0f, a0 = 0.0f, a1 = 0.0f, a2 = 0.0f;
  int jlo = rowstart[i], jhi = jlo + cnt[i];
  int j = jlo;
  for (; j + 1 < jhi; j += 2) {
    int s0 = srcs[j];
    int s1 = srcs[j + 1];
    const bf16* sop0 = so + (size_t)s0 * F3H;
    const bf16* sop1 = so + (size_t)s1 * F3H;
    float sA0 = b2f(sop0[h]), sB0 = b2f(sop0[H + h]), sC0 = b2f(sop0[2 * H + h]);
    float sA1 = b2f(sop1[h]), sB1 = b2f(sop1[H + h]), sC1 = b2f(sop1[2 * H + h]);
    float nA0, nB0, nC0, nA1, nB1, nC1;
    if (HASNV) {
      const bf16* nvp0 = nvb16 + (size_t)s0 * F3H;
      const bf16* nvp1 = nvb16 + (size_t)s1 * F3H;
      nA0 = b2f(nvp0[h]); nB0 = b2f(nvp0[H + h]); nC0 = b2f(nvp0[2 * H + h]);
      nA1 = b2f(nvp1[h]); nB1 = b2f(nvp1[H + h]); nC1 = b2f(nvp1[2 * H + h]);
    }

    {
      const float* g = geo + (size_t)j * 24;
      float gg[24];
      #pragma unroll
      for (int q = 0; q < 6; q++) *(float4*)&gg[4 * q] = *(const float4*)&g[4 * q];
      float fc = gg[23];
      float f0 = bb0 * fc, f1 = bb1 * fc, f2 = bb2 * fc;
      #pragma unroll
      for (int k = 0; k < E_RBF; k++) {
        float rk = gg[k];
        f0 += rk * wf0[k];
        f1 += rk * wf1[k];
        f2 += rk * wf2[k];
      }
      float u0 = gg[20], u1 = gg[21], u2 = gg[22];
      float gsv = f0 * sA0;
      float gev = f1 * sB0;
      accs += f2 * sC0;
      if (HASNV) {
        a0 += nA0 * gsv + gev * u0;
        a1 += nB0 * gsv + gev * u1;
        a2 += nC0 * gsv + gev * u2;
      } else {
        a0 += gev * u0;
        a1 += gev * u1;
        a2 += gev * u2;
      }
    }
    {
      const float* g = geo + (size_t)(j + 1) * 24;
      float gg[24];
      #pragma unroll
      for (int q = 0; q < 6; q++) *(float4*)&gg[4 * q] = *(const float4*)&g[4 * q];
      float fc = gg[23];
      float f0 = bb0 * fc, f1 = bb1 * fc, f2 = bb2 * fc;
      #pragma unroll
      for (int k = 0; k < E_RBF; k++) {
        float rk = gg[k];
        f0 += rk * wf0[k];
        f1 += rk * wf1[k];
        f2 += rk * wf2[k];
      }
      float u0 = gg[20], u1 = gg[21], u2 = gg[22];
      float gsv = f0 * sA1;
      float gev = f1 * sB1;
      accs += f2 * sC1;
      if (HASNV) {
        a0 += nA1 * gsv + gev * u0;
        a1 += nB1 * gsv + gev * u1;
        a2 += nC1 * gsv + gev * u2;
      } else {
        a0 += gev * u0;
        a1 += gev * u1;
        a2 += gev * u2;
      }
    }
  }
  if (j < jhi) {
    int src = srcs[j];
    const float* g = geo + (size_t)j * 24;
    float gg[24];
    #pragma unroll
    for (int q = 0; q < 6; q++) *(float4*)&gg[4 * q] = *(const float4*)&g[4 * q];
    float fc = gg[23];
    float f0 = bb0 * fc, f1 = bb1 * fc, f2 = bb2 * fc;
    #pragma unroll
    for (int k = 0; k < E_RBF; k++) {
      float rk = gg[k];
      f0 += rk * wf0[k];
      f1 += rk * wf1[k];
      f2 += rk * wf2[k];
    }
    float u0 = gg[20], u1 = gg[21], u2 = gg[22];
    const bf16* sop = so + (size_t)src * F3H;
    float gsv = f0 * b2f(sop[h]);
    float gev = f1 * b2f(sop[H + h]);
    accs += f2 * b2f(sop[2 * H + h]);
    if (HASNV) {
      const bf16* nvp = nvb16 + (size_t)src * F3H;
      a0 += b2f(nvp[h])         * gsv + gev * u0;
      a1 += b2f(nvp[H + h])     * gsv + gev * u1;
      a2 += b2f(nvp[2 * H + h]) * gsv + gev * u2;
    } else {
      a0 += gev * u0;
      a1 += gev * u1;
      a2 += gev * u2;
    }
  }

  float ns_new = ns[(size_t)i * H + h] + accs;
  ns[(size_t)i * H + h] = ns_new;
  nsmsg[(size_t)i * H + h] = __float2bfloat16(ns_new);
  float o0, o1, o2;
  if (HASNV) {
    const float* nvi = nvA + (size_t)i * F3H;
    o0 = nvi[h] + a0;
    o1 = nvi[H + h] + a1;
    o2 = nvi[2 * H + h] + a2;
  } else {
    o0 = a0; o1 = a1; o2 = a2;
  }
  nvB[(size_t)i * F3H + h]         = o0;
  nvB[(size_t)i * F3H + H + h]     = o1;
  nvB[(size_t)i * F3H + 2 * H + h] = o2;
  nvmsg16[(size_t)i * F3H + h]         = __float2bfloat16(o0);
  nvmsg16[(size_t)i * F3H + H + h]     = __float2bfloat16(o1);
  nvmsg16[(size_t)i * F3H + 2 * H + h] = __float2bfloat16(o2);
}

extern "C" void kernel_launch(void* const* d_in, const int* in_sizes, int n_in,
                              void* d_out, int out_size, void* d_ws, size_t ws_size,
                              hipStream_t stream) {
  const int*   z     = (const int*)d_in[0];
  const int*   edge  = (const int*)d_in[1];
  const float* ediff = (const float*)d_in[2];
  const float* edist = (const float*)d_in[3];
  const float* embed = (const float*)d_in[4];
  const float* mfw   = (const float*)d_in[5];
  const float* mfb   = (const float*)d_in[6];
  const float* mw1   = (const float*)d_in[7];
  const float* mb1   = (const float*)d_in[8];
  const float* mw2   = (const float*)d_in[9];
  const float* mb2   = (const float*)d_in[10];
  const float* uUw   = (const float*)d_in[11];
  const float* uUb   = (const float*)d_in[12];
  const float* uVw   = (const float*)d_in[13];
  const float* uVb   = (const float*)d_in[14];
  const float* uw1   = (const float*)d_in[15];
  const float* ub1   = (const float*)d_in[16];
  const float* uw2   = (const float*)d_in[17];
  const float* ub2   = (const float*)d_in[18];
  const float* rw1   = (const float*)d_in[19];
  const float* rb1   = (const float*)d_in[20];
  const float* rw2   = (const float*)d_in[21];
  const float* rb2   = (const float*)d_in[22];

  const int N  = in_sizes[0];   // 10000
  const int nE = in_sizes[3];   // 160000

  float* ws = (float*)d_ws;
  size_t off = 0;
  float* ns      = ws + off; off += (size_t)N * H;
  float* nvA     = ws + off; off += (size_t)N * F3H;
  float* nvB     = ws + off; off += (size_t)N * F3H;
  float* geo     = ws + off; off += (size_t)nE * 24;
  bf16* so       = (bf16*)(ws + off); off += (size_t)N * F3H / 2;
  bf16* nvb16    = (bf16*)(ws + off); off += (size_t)N * F3H / 2;
  bf16* nvmsg16  = (bf16*)(ws + off); off += (size_t)N * F3H / 2;
  bf16* nsmsg    = (bf16*)(ws + off); off += (size_t)N * 64;        // N*128 bf16
  bf16* ns16     = (bf16*)(ws + off); off += (size_t)N * 64;        // N*128 bf16 (l0 only)
  bf16* wpack    = (bf16*)(ws + off); off += 3 * 2 * 16384 / 2;     // UV
  bf16* wp_m1    = (bf16*)(ws + off); off += 3 * 256 * 128 / 2;
  bf16* wp_m2    = (bf16*)(ws + off); off += 3 * 128 * 384 / 2;
  bf16* wp_sm1   = (bf16*)(ws + off); off += 3 * 128 * 128 / 2;
  bf16* wp_sm2   = (bf16*)(ws + off); off += 3 * 128 * 384 / 2;
  bf16* wp_ro1   = (bf16*)(ws + off); off += 128 * 128 / 2;
  bf16* wp_ro2   = (bf16*)(ws + off); off += 128 * 128 / 2;
  int* srcs     = (int*)(ws + off); off += nE;
  int* cnt      = (int*)(ws + off); off += N;
  int* rowstart = (int*)(ws + off); off += N;
  int* cur      = (int*)(ws + off); off += N;

  const int tilesN = (N + 31) / 32;            // 313
  const int tilesUV = (N + 15) / 16;           // 625

  pack_all<<<1024, 256, 0, stream>>>(
      uUw, uVw, wpack, uw1, wp_m1, uw2, wp_m2, mw1, wp_sm1, mw2, wp_sm2,
      rw1, wp_ro1, rw2, wp_ro2, z, embed, ns, ns16, cnt, N);
  csr_hist<<<(nE + 255) / 256, 256, 0, stream>>>(edge, cnt, nE);
  csr_scan<<<1, 1024, 0, stream>>>(cnt, rowstart, cur, N);
  csr_fill_pack<<<(nE + 255) / 256, 256, 0, stream>>>(edge, cur, edist, ediff, srcs, geo, nE);

  float* nv_cur = nvA;
  float* nv_nxt = nvB;
  for (int l = 0; l < NLAYER; l++) {
    if (l == 0)
      mlp_msg<<<tilesN, 256, 0, stream>>>(
          ns16, wp_sm1, mb1, wp_sm2, mb2, so, N);

    if (l == 0)
      message3<false><<<N, H, 0, stream>>>(srcs, rowstart, cnt, geo,
                                           mfw + (size_t)l * E_RBF * F3H, mfb + (size_t)l * F3H,
                                           so, nvb16, nv_cur, ns, nv_nxt, nvmsg16, nsmsg, N);
    else
      message3<true><<<N, H, 0, stream>>>(srcs, rowstart, cnt, geo,
                                          mfw + (size_t)l * E_RBF * F3H, mfb + (size_t)l * F3H,
                                          so, nvb16, nv_cur, ns, nv_nxt, nvmsg16, nsmsg, N);

    if (l < NLAYER - 1) {
      uv_upd<0><<<tilesUV, 512, 0, stream>>>(
          nvmsg16, wpack + (size_t)l * 2 * 16384,
          uUb + (size_t)l * H, uVb + (size_t)l * H,
          nsmsg,
          wp_m1 + (size_t)l * 256 * 128, ub1 + (size_t)l * H,
          wp_m2 + (size_t)l * 128 * 384, ub2 + (size_t)l * F3H,
          ns, nv_nxt, nvb16,
          wp_sm1 + (size_t)(l + 1) * 128 * 128, mb1 + (size_t)(l + 1) * H,
          wp_sm2 + (size_t)(l + 1) * 128 * 384, mb2 + (size_t)(l + 1) * F3H,
          so, nullptr, N);
    } else {
      uv_upd<1><<<tilesUV, 512, 0, stream>>>(
          nvmsg16, wpack + (size_t)l * 2 * 16384,
          uUb + (size_t)l * H, uVb + (size_t)l * H,
          nsmsg,
          wp_m1 + (size_t)l * 256 * 128, ub1 + (size_t)l * H,
          wp_m2 + (size_t)l * 128 * 384, ub2 + (size_t)l * F3H,
          ns, nv_nxt, nvb16,
          wp_ro1, rb1, wp_ro2, rb2,
          nullptr, (float*)d_out, N);
    }

    float* t = nv_cur; nv_cur = nv_nxt; nv_nxt = t;
  }
}